// Round 1
// baseline (401.509 us; speedup 1.0000x reference)
//
#include <hip/hip_runtime.h>
#include <hip/hip_bf16.h>

typedef unsigned short u16;
typedef unsigned int   u32;
typedef __attribute__((ext_vector_type(8))) short bf16x8;
typedef __attribute__((ext_vector_type(4))) float f32x4;

// Problem constants
#define B_   2
#define S_   2048
#define HID_ 2048
#define NH_  32
#define HKV_ 8
#define HD_  64
#define NQK  512      // HKV*HD
#define NTOT 3072     // 512+512+2048
#define MROWS 4096    // B*S

__device__ __forceinline__ u16 f2bf(float f) {            // RNE float->bf16
  u32 x = __float_as_uint(f);
  x += 0x7fffu + ((x >> 16) & 1u);
  return (u16)(x >> 16);
}
__device__ __forceinline__ float bf2f(u16 u) { return __uint_as_float(((u32)u) << 16); }
__device__ __forceinline__ u32 pack2bf(float a, float b) {
  return (u32)f2bf(a) | ((u32)f2bf(b) << 16);
}

// ---------------------------------------------------------------- prep: A fp32 -> bf16
__global__ __launch_bounds__(256) void cvtA_kernel(const float* __restrict__ A,
                                                   u16* __restrict__ Abf) {
  const int n4 = (MROWS * HID_) / 4;  // 2,097,152 float4s
  int i = blockIdx.x * blockDim.x + threadIdx.x;
  for (int idx = i; idx < n4; idx += gridDim.x * blockDim.x) {
    float4 v = ((const float4*)A)[idx];
    ushort4 o;
    o.x = f2bf(v.x); o.y = f2bf(v.y); o.z = f2bf(v.z); o.w = f2bf(v.w);
    ((ushort4*)Abf)[idx] = o;
  }
}

// ---------------------------------------------------------------- prep: W -> Wt bf16 (transposed, concatenated)
// Wt[n][k] for n in [0,3072): n<512 -> Wq, n<1024 -> Wk, else Wv
__global__ __launch_bounds__(256) void cvtW_kernel(const float* __restrict__ Wq,
                                                   const float* __restrict__ Wk,
                                                   const float* __restrict__ Wv,
                                                   u16* __restrict__ Wt) {
  int n0 = blockIdx.x * 32, k0 = blockIdx.y * 32;
  const float* src; int ld, nn;
  if (n0 < 512)       { src = Wq; nn = n0;        ld = 512;  }
  else if (n0 < 1024) { src = Wk; nn = n0 - 512;  ld = 512;  }
  else                { src = Wv; nn = n0 - 1024; ld = 2048; }
  __shared__ float tile[32][33];
  int tx = threadIdx.x, ty = threadIdx.y;
#pragma unroll
  for (int i = 0; i < 4; i++) {
    int kk = k0 + ty + i * 8;
    tile[ty + i * 8][tx] = src[(size_t)kk * ld + nn + tx];
  }
  __syncthreads();
#pragma unroll
  for (int i = 0; i < 4; i++) {
    int nrow = ty + i * 8;
    Wt[(size_t)(n0 + nrow) * HID_ + k0 + tx] = f2bf(tile[tx][nrow]);
  }
}

// ---------------------------------------------------------------- GEMM: QKV = Abf(4096x2048) * Wt^T  -> bf16 (4096x3072)
// 128x128 tile, BK=64, 4 waves (2x2), wave tile 64x64 via 16x16x32 bf16 MFMA.
// Reg-staged LDS with 16B-subtile XOR swizzle (sub ^= row&7) for conflict-free ds_read_b128.
__global__ __launch_bounds__(256) void gemm_kernel(const u16* __restrict__ A,
                                                   const u16* __restrict__ Bt,
                                                   u16* __restrict__ C) {
  __shared__ u16 As[128 * 64];
  __shared__ u16 Bs[128 * 64];
  bf16x8* Asv = (bf16x8*)As;
  bf16x8* Bsv = (bf16x8*)Bs;
  int tid = threadIdx.x, l = tid & 63, wid = tid >> 6;
  int l15 = l & 15, lg = l >> 4;
  int bm = blockIdx.y * 128, bn = blockIdx.x * 128;
  int wr = (wid >> 1) * 64, wc = (wid & 1) * 64;
  f32x4 acc[4][4] = {};
  int r0 = tid >> 3, s0 = tid & 7;   // staging chunk: row r0 + 32*i, 16B subtile s0
  for (int kt = 0; kt < HID_ / 64; kt++) {
    int k0 = kt * 64;
    // issue global loads before the barrier (overlap with previous compute)
    bf16x8 va[4], vb[4];
#pragma unroll
    for (int i = 0; i < 4; i++) {
      int r = r0 + 32 * i;
      va[i] = *(const bf16x8*)(A  + (size_t)(bm + r) * HID_ + k0 + s0 * 8);
      vb[i] = *(const bf16x8*)(Bt + (size_t)(bn + r) * HID_ + k0 + s0 * 8);
    }
    __syncthreads();   // previous iteration's LDS reads complete
#pragma unroll
    for (int i = 0; i < 4; i++) {
      int r = r0 + 32 * i;
      Asv[r * 8 + (s0 ^ (r & 7))] = va[i];
      Bsv[r * 8 + (s0 ^ (r & 7))] = vb[i];
    }
    __syncthreads();
#pragma unroll
    for (int kc = 0; kc < 2; kc++) {
      bf16x8 af[4], bfr[4];
      int sub = kc * 4 + lg;
#pragma unroll
      for (int m = 0; m < 4; m++) {
        int row = wr + m * 16 + l15;
        af[m] = Asv[row * 8 + (sub ^ (row & 7))];
      }
#pragma unroll
      for (int n = 0; n < 4; n++) {
        int row = wc + n * 16 + l15;
        bfr[n] = Bsv[row * 8 + (sub ^ (row & 7))];
      }
#pragma unroll
      for (int m = 0; m < 4; m++)
#pragma unroll
        for (int n = 0; n < 4; n++)
          acc[m][n] = __builtin_amdgcn_mfma_f32_16x16x32_bf16(af[m], bfr[n], acc[m][n], 0, 0, 0);
    }
  }
  // epilogue: C layout col=lane&15, row=(lane>>4)*4+j
#pragma unroll
  for (int m = 0; m < 4; m++)
#pragma unroll
    for (int n = 0; n < 4; n++) {
      int col  = bn + wc + n * 16 + l15;
      int rowb = bm + wr + m * 16 + lg * 4;
#pragma unroll
      for (int j = 0; j < 4; j++)
        C[(size_t)(rowb + j) * NTOT + col] = f2bf(acc[m][n][j]);
    }
}

// ---------------------------------------------------------------- RoPE on Q,K; Q scaled by 1/8.
// Qr/Kr layout: [b][hkv][s][d] bf16
__global__ __launch_bounds__(128) void rope_kernel(const u16* __restrict__ QKV,
                                                   const int* __restrict__ pos_ids,
                                                   u16* __restrict__ Qr,
                                                   u16* __restrict__ Kr) {
  int bs = blockIdx.x;            // b*2048+s
  int b = bs >> 11, s = bs & 2047;
  __shared__ float cs[32], sn[32];
  int t = threadIdx.x;
  if (t < 32) {
    float inv = expf(-((float)(2 * t) / 64.0f) * logf(10000.0f));
    float ang = (float)pos_ids[bs] * inv;
    cs[t] = cosf(ang);
    sn[t] = sinf(ang);
  }
  __syncthreads();
  const u16* row = QKV + (size_t)bs * NTOT;
#pragma unroll
  for (int i = 0; i < 4; i++) {
    int e = t + i * 128;          // 0..511
    int h = e >> 6, d = e & 63, j = d & 31;
    int ep = (d < 32) ? e + 32 : e - 32;
    size_t dst = (((size_t)(b * HKV_ + h) * S_ + s) * HD_) + d;
    float xq = bf2f(row[e]),        xq2 = bf2f(row[ep]);
    float xk = bf2f(row[NQK + e]),  xk2 = bf2f(row[NQK + ep]);
    float qv = (d < 32) ? xq * cs[j] - xq2 * sn[j] : xq * cs[j] + xq2 * sn[j];
    float kv = (d < 32) ? xk * cs[j] - xk2 * sn[j] : xk * cs[j] + xk2 * sn[j];
    Qr[dst] = f2bf(qv * 0.125f);  // fold 1/sqrt(64) into Q
    Kr[dst] = f2bf(kv);
  }
}

// ---------------------------------------------------------------- V -> Vt [b][h][d][s] bf16 (transposed for PV B-operand)
__global__ __launch_bounds__(256) void transV_kernel(const u16* __restrict__ QKV,
                                                     u16* __restrict__ Vt) {
  int st = blockIdx.x, h = blockIdx.y, b = blockIdx.z;
  __shared__ u16 tile[64][65];
  int t = threadIdx.x;
#pragma unroll
  for (int i = 0; i < 16; i++) {
    int idx = t + i * 256;            // 0..4095
    int r = idx >> 6, d = idx & 63;   // r = s within tile
    tile[r][d] = QKV[(size_t)(b * S_ + st * 64 + r) * NTOT + 1024 + h * 64 + d];
  }
  __syncthreads();
#pragma unroll
  for (int i = 0; i < 16; i++) {
    int idx = t + i * 256;
    int d = idx >> 6, ss = idx & 63;
    Vt[((size_t)(b * NH_ + h) * HD_ + d) * S_ + st * 64 + ss] = tile[ss][d];
  }
}

// ---------------------------------------------------------------- causal GQA flash attention
// 1 wave per block, 32 q-rows per wave, 64-key tiles, swapped QK^T (S^T = mfma(K, Q)).
// K/V read direct from global (L2-resident per head). P via 4KB swizzled LDS.
__global__ __launch_bounds__(64) void attn_kernel(const u16* __restrict__ Qr,
                                                  const u16* __restrict__ Kr,
                                                  const u16* __restrict__ Vt,
                                                  float* __restrict__ Out) {
  int qt = blockIdx.x;               // 0..63: qb = qt*32
  int h  = blockIdx.y, b = blockIdx.z;
  int hk = h & (HKV_ - 1);
  int l = threadIdx.x, l15 = l & 15, g = l >> 4;
  int qb = qt * 32;

  __shared__ u16 Plds[32 * 64];      // 32 q-rows x 64 keys, XOR-swizzled 16B subtiles

  const u16* Qbase = Qr + (size_t)(b * HKV_ + hk) * S_ * HD_;
  const u16* Kbase = Kr + (size_t)(b * HKV_ + hk) * S_ * HD_;
  const u16* Vbase = Vt + (size_t)(b * NH_ + h) * HD_ * S_;

  // Q as B-operand frags: q = qb + nq*16 + l15 (col), d = kc*32 + g*8
  bf16x8 bq[2][2];
#pragma unroll
  for (int nq = 0; nq < 2; nq++)
#pragma unroll
    for (int kc = 0; kc < 2; kc++)
      bq[nq][kc] = *(const bf16x8*)(Qbase + (size_t)(qb + nq * 16 + l15) * HD_ + kc * 32 + g * 8);

  f32x4 O[2][4] = {};                        // [m(q-block)][nd(d-block)]
  float mS[2] = {-1e30f, -1e30f}, lS[2] = {0.f, 0.f};

  int ntiles = (qb + 95) >> 6;               // keys up to qb+31 covered
  for (int kt = 0; kt < ntiles; kt++) {
    // --- S^T = K * Q : rows=keys, cols=q
    f32x4 sacc[4][2] = {};
#pragma unroll
    for (int kc = 0; kc < 2; kc++) {
      bf16x8 ka[4];
#pragma unroll
      for (int mk = 0; mk < 4; mk++)
        ka[mk] = *(const bf16x8*)(Kbase + (size_t)(kt * 64 + mk * 16 + l15) * HD_ + kc * 32 + g * 8);
#pragma unroll
      for (int mk = 0; mk < 4; mk++)
#pragma unroll
        for (int nq = 0; nq < 2; nq++)
          sacc[mk][nq] = __builtin_amdgcn_mfma_f32_16x16x32_bf16(ka[mk], bq[nq][kc], sacc[mk][nq], 0, 0, 0);
    }
    // --- causal mask + column(=q) max
    float tmax[2] = {-1e30f, -1e30f};
#pragma unroll
    for (int mk = 0; mk < 4; mk++)
#pragma unroll
      for (int nq = 0; nq < 2; nq++)
#pragma unroll
        for (int j = 0; j < 4; j++) {
          int key = kt * 64 + mk * 16 + g * 4 + j;
          int q   = qb + nq * 16 + l15;
          float s = (key <= q) ? sacc[mk][nq][j] : -1e30f;
          sacc[mk][nq][j] = s;
          tmax[nq] = fmaxf(tmax[nq], s);
        }
#pragma unroll
    for (int nq = 0; nq < 2; nq++) {
      tmax[nq] = fmaxf(tmax[nq], __shfl_xor(tmax[nq], 16));
      tmax[nq] = fmaxf(tmax[nq], __shfl_xor(tmax[nq], 32));
    }
    float alpha[2], mnew[2];
#pragma unroll
    for (int nq = 0; nq < 2; nq++) {
      mnew[nq]  = fmaxf(mS[nq], tmax[nq]);
      alpha[nq] = __expf(mS[nq] - mnew[nq]);
      mS[nq]    = mnew[nq];
    }
    // --- P = exp(S - m), pack bf16, column sum
    float tsum[2] = {0.f, 0.f};
    u32 upk[2][4][2];
#pragma unroll
    for (int nq = 0; nq < 2; nq++)
#pragma unroll
      for (int mk = 0; mk < 4; mk++) {
        float p0 = __expf(sacc[mk][nq][0] - mnew[nq]);
        float p1 = __expf(sacc[mk][nq][1] - mnew[nq]);
        float p2 = __expf(sacc[mk][nq][2] - mnew[nq]);
        float p3 = __expf(sacc[mk][nq][3] - mnew[nq]);
        tsum[nq] += (p0 + p1) + (p2 + p3);
        upk[nq][mk][0] = pack2bf(p0, p1);
        upk[nq][mk][1] = pack2bf(p2, p3);
      }
#pragma unroll
    for (int nq = 0; nq < 2; nq++) {
      tsum[nq] += __shfl_xor(tsum[nq], 16);
      tsum[nq] += __shfl_xor(tsum[nq], 32);
      lS[nq] = lS[nq] * alpha[nq] + tsum[nq];
    }
    // --- write P^T-holder to LDS (row = q_local, keys contiguous), swizzled
#pragma unroll
    for (int nq = 0; nq < 2; nq++)
#pragma unroll
      for (int mk = 0; mk < 4; mk++) {
        int ql  = nq * 16 + l15;
        int sub = mk * 2 + (g >> 1);
        int byteoff = ql * 128 + ((sub ^ (ql & 7)) * 16) + (g & 1) * 8;
        *(uint2*)((char*)Plds + byteoff) = make_uint2(upk[nq][mk][0], upk[nq][mk][1]);
      }
    // --- rescale O by alpha (broadcast per O-row via shfl)
#pragma unroll
    for (int m = 0; m < 2; m++)
#pragma unroll
      for (int j = 0; j < 4; j++) {
        float a = __shfl(alpha[m], g * 4 + j);
#pragma unroll
        for (int nd = 0; nd < 4; nd++)
          O[m][nd][j] *= a;
      }
    // --- O += P * V
#pragma unroll
    for (int kc = 0; kc < 2; kc++) {
      bf16x8 pa[2], vb[4];
#pragma unroll
      for (int m = 0; m < 2; m++) {
        int ql  = m * 16 + l15;
        int sub = kc * 4 + g;
        pa[m] = *(bf16x8*)((char*)Plds + ql * 128 + ((sub ^ (ql & 7)) * 16));
      }
#pragma unroll
      for (int nd = 0; nd < 4; nd++) {
        int d = nd * 16 + l15;
        vb[nd] = *(const bf16x8*)(Vbase + (size_t)d * S_ + kt * 64 + kc * 32 + g * 8);
      }
#pragma unroll
      for (int m = 0; m < 2; m++)
#pragma unroll
        for (int nd = 0; nd < 4; nd++)
          O[m][nd] = __builtin_amdgcn_mfma_f32_16x16x32_bf16(pa[m], vb[nd], O[m][nd], 0, 0, 0);
    }
  }
  // --- normalize + write fp32 output [b][q][h*64+d]
  float linv[2];
#pragma unroll
  for (int m = 0; m < 2; m++) linv[m] = 1.0f / lS[m];
#pragma unroll
  for (int m = 0; m < 2; m++)
#pragma unroll
    for (int j = 0; j < 4; j++) {
      float li = __shfl(linv[m], g * 4 + j);
      int q = qb + m * 16 + g * 4 + j;
#pragma unroll
      for (int nd = 0; nd < 4; nd++) {
        int d = nd * 16 + l15;
        Out[(size_t)(b * S_ + q) * HID_ + h * 64 + d] = O[m][nd][j] * li;
      }
    }
}

// ---------------------------------------------------------------- launch
extern "C" void kernel_launch(void* const* d_in, const int* in_sizes, int n_in,
                              void* d_out, int out_size, void* d_ws, size_t ws_size,
                              hipStream_t stream) {
  const float* hs  = (const float*)d_in[0];
  const int*   pos = (const int*)d_in[1];
  const float* Wq  = (const float*)d_in[2];
  const float* Wk  = (const float*)d_in[3];
  const float* Wv  = (const float*)d_in[4];
  float* out = (float*)d_out;
  char* ws = (char*)d_ws;
  // workspace layout (bytes): total 79,691,776
  u16* Abf = (u16*)(ws + 0);          // 4096*2048*2 = 16,777,216
  u16* Wt  = (u16*)(ws + 16777216);   // 3072*2048*2 = 12,582,912
  u16* QKV = (u16*)(ws + 29360128);   // 4096*3072*2 = 25,165,824
  u16* Qr  = (u16*)(ws + 54525952);   // 2*8*2048*64*2 = 4,194,304
  u16* Kr  = (u16*)(ws + 58720256);   // 4,194,304
  u16* Vt  = (u16*)(ws + 62914560);   // 2*32*64*2048*2 = 16,777,216

  cvtA_kernel<<<dim3(2048), dim3(256), 0, stream>>>(hs, Abf);
  cvtW_kernel<<<dim3(96, 64), dim3(32, 8), 0, stream>>>(Wq, Wk, Wv, Wt);
  gemm_kernel<<<dim3(24, 32), dim3(256), 0, stream>>>(Abf, Wt, QKV);
  rope_kernel<<<dim3(4096), dim3(128), 0, stream>>>(QKV, pos, Qr, Kr);
  transV_kernel<<<dim3(32, 32, 2), dim3(256), 0, stream>>>(QKV, Vt);
  attn_kernel<<<dim3(64, 32, 2), dim3(64), 0, stream>>>(Qr, Kr, Vt, out);
}

// Round 2
// 286.508 us; speedup vs baseline: 1.4014x; 1.4014x over previous
//
#include <hip/hip_runtime.h>
#include <hip/hip_bf16.h>

typedef unsigned short u16;
typedef unsigned int   u32;
typedef __attribute__((ext_vector_type(8))) short bf16x8;
typedef __attribute__((ext_vector_type(4))) float f32x4;

// Problem constants
#define B_   2
#define S_   2048
#define HID_ 2048
#define NH_  32
#define HKV_ 8
#define HD_  64
#define NQK  512      // HKV*HD
#define NTOT 3072     // 512+512+2048
#define MROWS 4096    // B*S

__device__ __forceinline__ u16 f2bf(float f) {            // RNE float->bf16
  u32 x = __float_as_uint(f);
  x += 0x7fffu + ((x >> 16) & 1u);
  return (u16)(x >> 16);
}
__device__ __forceinline__ float bf2f(u16 u) { return __uint_as_float(((u32)u) << 16); }
__device__ __forceinline__ u32 pack2bf(float a, float b) {
  return (u32)f2bf(a) | ((u32)f2bf(b) << 16);
}

__device__ __forceinline__ void gload16(const u16* g, u16* l) {
  __builtin_amdgcn_global_load_lds((const __attribute__((address_space(1))) void*)g,
                                   (__attribute__((address_space(3))) void*)l, 16, 0, 0);
}

// ---------------------------------------------------------------- prep: A fp32 -> bf16
__global__ __launch_bounds__(256) void cvtA_kernel(const float* __restrict__ A,
                                                   u16* __restrict__ Abf) {
  const int n4 = (MROWS * HID_) / 4;
  int i = blockIdx.x * blockDim.x + threadIdx.x;
  for (int idx = i; idx < n4; idx += gridDim.x * blockDim.x) {
    float4 v = ((const float4*)A)[idx];
    ushort4 o;
    o.x = f2bf(v.x); o.y = f2bf(v.y); o.z = f2bf(v.z); o.w = f2bf(v.w);
    ((ushort4*)Abf)[idx] = o;
  }
}

// ---------------------------------------------------------------- prep: W -> Wt bf16 (transposed, concatenated)
__global__ __launch_bounds__(256) void cvtW_kernel(const float* __restrict__ Wq,
                                                   const float* __restrict__ Wk,
                                                   const float* __restrict__ Wv,
                                                   u16* __restrict__ Wt) {
  int n0 = blockIdx.x * 32, k0 = blockIdx.y * 32;
  const float* src; int ld, nn;
  if (n0 < 512)       { src = Wq; nn = n0;        ld = 512;  }
  else if (n0 < 1024) { src = Wk; nn = n0 - 512;  ld = 512;  }
  else                { src = Wv; nn = n0 - 1024; ld = 2048; }
  __shared__ float tile[32][33];
  int tx = threadIdx.x, ty = threadIdx.y;
#pragma unroll
  for (int i = 0; i < 4; i++) {
    int kk = k0 + ty + i * 8;
    tile[ty + i * 8][tx] = src[(size_t)kk * ld + nn + tx];
  }
  __syncthreads();
#pragma unroll
  for (int i = 0; i < 4; i++) {
    int nrow = ty + i * 8;
    Wt[(size_t)(n0 + nrow) * HID_ + k0 + tx] = f2bf(tile[tx][nrow]);
  }
}

// ---------------------------------------------------------------- GEMM: QKV = Abf(4096x2048) * Wt^T -> bf16 (4096x3072)
// 128x128 tile, BK=64, 4 waves. global_load_lds width-16 staging: linear LDS
// dest + inverse-swizzled global source; swizzled ds_read_b128 (involution XOR).
__global__ __launch_bounds__(256) void gemm_kernel(const u16* __restrict__ A,
                                                   const u16* __restrict__ Bt,
                                                   u16* __restrict__ C) {
  __shared__ u16 As[128 * 64];
  __shared__ u16 Bs[128 * 64];
  bf16x8* Asv = (bf16x8*)As;
  bf16x8* Bsv = (bf16x8*)Bs;
  int tid = threadIdx.x, l = tid & 63, wid = tid >> 6;
  int l15 = l & 15, lg = l >> 4;
  int bm = blockIdx.y * 128, bn = blockIdx.x * 128;
  int wr = (wid >> 1) * 64, wc = (wid & 1) * 64;
  f32x4 acc[4][4] = {};
  // per-lane source mapping for 4 staging calls: slot = i*256 + tid (16B units)
  int r_[4], c_[4];
#pragma unroll
  for (int i = 0; i < 4; i++) {
    int slot = i * 256 + tid;
    int r = slot >> 3, sub = slot & 7;
    r_[i] = r;
    c_[i] = (sub ^ (r & 7)) << 3;   // element col offset within K-tile
  }
  for (int kt = 0; kt < HID_ / 64; kt++) {
    int k0 = kt * 64;
    __syncthreads();               // all waves done reading previous tile
#pragma unroll
    for (int i = 0; i < 4; i++)
      gload16(A + (size_t)(bm + r_[i]) * HID_ + k0 + c_[i], (u16*)&Asv[i * 256 + wid * 64]);
#pragma unroll
    for (int i = 0; i < 4; i++)
      gload16(Bt + (size_t)(bn + r_[i]) * HID_ + k0 + c_[i], (u16*)&Bsv[i * 256 + wid * 64]);
    __syncthreads();               // drains vmcnt -> LDS data visible
#pragma unroll
    for (int kc = 0; kc < 2; kc++) {
      bf16x8 af[4], bfr[4];
      int sub = kc * 4 + lg;
#pragma unroll
      for (int m = 0; m < 4; m++) {
        int row = wr + m * 16 + l15;
        af[m] = Asv[row * 8 + (sub ^ (row & 7))];
      }
#pragma unroll
      for (int n = 0; n < 4; n++) {
        int row = wc + n * 16 + l15;
        bfr[n] = Bsv[row * 8 + (sub ^ (row & 7))];
      }
#pragma unroll
      for (int m = 0; m < 4; m++)
#pragma unroll
        for (int n = 0; n < 4; n++)
          acc[m][n] = __builtin_amdgcn_mfma_f32_16x16x32_bf16(af[m], bfr[n], acc[m][n], 0, 0, 0);
    }
  }
#pragma unroll
  for (int m = 0; m < 4; m++)
#pragma unroll
    for (int n = 0; n < 4; n++) {
      int col  = bn + wc + n * 16 + l15;
      int rowb = bm + wr + m * 16 + lg * 4;
#pragma unroll
      for (int j = 0; j < 4; j++)
        C[(size_t)(rowb + j) * NTOT + col] = f2bf(acc[m][n][j]);
    }
}

// ---------------------------------------------------------------- RoPE on Q,K; Q scaled by 1/8.
__global__ __launch_bounds__(128) void rope_kernel(const u16* __restrict__ QKV,
                                                   const int* __restrict__ pos_ids,
                                                   u16* __restrict__ Qr,
                                                   u16* __restrict__ Kr) {
  int bs = blockIdx.x;
  int b = bs >> 11, s = bs & 2047;
  __shared__ float cs[32], sn[32];
  int t = threadIdx.x;
  if (t < 32) {
    float inv = expf(-((float)(2 * t) / 64.0f) * logf(10000.0f));
    float ang = (float)pos_ids[bs] * inv;
    cs[t] = cosf(ang);
    sn[t] = sinf(ang);
  }
  __syncthreads();
  const u16* row = QKV + (size_t)bs * NTOT;
#pragma unroll
  for (int i = 0; i < 4; i++) {
    int e = t + i * 128;
    int h = e >> 6, d = e & 63, j = d & 31;
    int ep = (d < 32) ? e + 32 : e - 32;
    size_t dst = (((size_t)(b * HKV_ + h) * S_ + s) * HD_) + d;
    float xq = bf2f(row[e]),        xq2 = bf2f(row[ep]);
    float xk = bf2f(row[NQK + e]),  xk2 = bf2f(row[NQK + ep]);
    float qv = (d < 32) ? xq * cs[j] - xq2 * sn[j] : xq * cs[j] + xq2 * sn[j];
    float kv = (d < 32) ? xk * cs[j] - xk2 * sn[j] : xk * cs[j] + xk2 * sn[j];
    Qr[dst] = f2bf(qv * 0.125f);
    Kr[dst] = f2bf(kv);
  }
}

// ---------------------------------------------------------------- V -> Vt [b][h][d][s] bf16
__global__ __launch_bounds__(256) void transV_kernel(const u16* __restrict__ QKV,
                                                     u16* __restrict__ Vt) {
  int st = blockIdx.x, h = blockIdx.y, b = blockIdx.z;
  __shared__ u16 tile[64][65];
  int t = threadIdx.x;
#pragma unroll
  for (int i = 0; i < 16; i++) {
    int idx = t + i * 256;
    int r = idx >> 6, d = idx & 63;
    tile[r][d] = QKV[(size_t)(b * S_ + st * 64 + r) * NTOT + 1024 + h * 64 + d];
  }
  __syncthreads();
#pragma unroll
  for (int i = 0; i < 16; i++) {
    int idx = t + i * 256;
    int d = idx >> 6, ss = idx & 63;
    Vt[((size_t)(b * NH_ + h) * HD_ + d) * S_ + st * 64 + ss] = tile[ss][d];
  }
}

// ---------------------------------------------------------------- causal GQA flash attention, GROUP-FUSED
// 1 wave per block, one kv-head, 4 V-heads. QK^T + softmax computed ONCE,
// PV applied to 4 heads. Swapped QK^T (S^T = mfma(K, Q)). K prefetch.
// qt remap balances per-CU causal work (blocks stride 256 share bx; (by>>2)&1 flips).
__global__ __launch_bounds__(64, 1) void attn_kernel(const u16* __restrict__ Qr,
                                                     const u16* __restrict__ Kr,
                                                     const u16* __restrict__ Vt,
                                                     float* __restrict__ Out) {
  int bx = blockIdx.x;               // 0..63
  int hk = blockIdx.y, b = blockIdx.z;
  int qt = ((hk >> 2) & 1) ? (63 - bx) : bx;
  int l = threadIdx.x, l15 = l & 15, g = l >> 4;
  int qb = qt * 32;

  __shared__ u16 Plds[32 * 64];      // 32 q-rows x 64 keys, XOR-swizzled 16B subtiles

  const u16* Qbase = Qr + (size_t)(b * HKV_ + hk) * S_ * HD_;
  const u16* Kbase = Kr + (size_t)(b * HKV_ + hk) * S_ * HD_;
  const u16* Vb[4];
#pragma unroll
  for (int r = 0; r < 4; r++)
    Vb[r] = Vt + (size_t)(b * NH_ + r * 8 + hk) * HD_ * S_;

  // Q as B-operand frags: q = qb + nq*16 + l15 (col), d = kc*32 + g*8
  bf16x8 bq[2][2];
#pragma unroll
  for (int nq = 0; nq < 2; nq++)
#pragma unroll
    for (int kc = 0; kc < 2; kc++)
      bq[nq][kc] = *(const bf16x8*)(Qbase + (size_t)(qb + nq * 16 + l15) * HD_ + kc * 32 + g * 8);

  f32x4 O[4][2][4] = {};             // [head r][m(q-block)][nd(d-block)]
  float mS[2] = {-1e30f, -1e30f}, lS[2] = {0.f, 0.f};

  int ntiles = (qb + 95) >> 6;

  // prefetch K frags for tile 0
  bf16x8 ka[2][4];
#pragma unroll
  for (int kc = 0; kc < 2; kc++)
#pragma unroll
    for (int mk = 0; mk < 4; mk++)
      ka[kc][mk] = *(const bf16x8*)(Kbase + (size_t)(mk * 16 + l15) * HD_ + kc * 32 + g * 8);

  for (int kt = 0; kt < ntiles; kt++) {
    // --- S^T = K * Q
    f32x4 sacc[4][2] = {};
#pragma unroll
    for (int kc = 0; kc < 2; kc++)
#pragma unroll
      for (int mk = 0; mk < 4; mk++)
#pragma unroll
        for (int nq = 0; nq < 2; nq++)
          sacc[mk][nq] = __builtin_amdgcn_mfma_f32_16x16x32_bf16(ka[kc][mk], bq[nq][kc], sacc[mk][nq], 0, 0, 0);
    // --- prefetch next K tile (clamped in-bounds; redundant on last iter)
    int ktn = (kt + 1 < ntiles) ? kt + 1 : kt;
    bf16x8 kan[2][4];
#pragma unroll
    for (int kc = 0; kc < 2; kc++)
#pragma unroll
      for (int mk = 0; mk < 4; mk++)
        kan[kc][mk] = *(const bf16x8*)(Kbase + (size_t)(ktn * 64 + mk * 16 + l15) * HD_ + kc * 32 + g * 8);
    // --- causal mask + column(=q) max
    float tmax[2] = {-1e30f, -1e30f};
#pragma unroll
    for (int mk = 0; mk < 4; mk++)
#pragma unroll
      for (int nq = 0; nq < 2; nq++)
#pragma unroll
        for (int j = 0; j < 4; j++) {
          int key = kt * 64 + mk * 16 + g * 4 + j;
          int q   = qb + nq * 16 + l15;
          float s = (key <= q) ? sacc[mk][nq][j] : -1e30f;
          sacc[mk][nq][j] = s;
          tmax[nq] = fmaxf(tmax[nq], s);
        }
#pragma unroll
    for (int nq = 0; nq < 2; nq++) {
      tmax[nq] = fmaxf(tmax[nq], __shfl_xor(tmax[nq], 16));
      tmax[nq] = fmaxf(tmax[nq], __shfl_xor(tmax[nq], 32));
    }
    // --- defer-max (T13): only rescale when max grew > 8
    bool need = (tmax[0] > mS[0] + 8.0f) || (tmax[1] > mS[1] + 8.0f);
    if (__any(need)) {
      float alpha[2];
#pragma unroll
      for (int nq = 0; nq < 2; nq++) {
        float mnew = fmaxf(mS[nq], tmax[nq]);
        alpha[nq] = __expf(mS[nq] - mnew);
        mS[nq] = mnew;
        lS[nq] *= alpha[nq];
      }
#pragma unroll
      for (int m = 0; m < 2; m++)
#pragma unroll
        for (int j = 0; j < 4; j++) {
          float a = __shfl(alpha[m], g * 4 + j);
#pragma unroll
          for (int r = 0; r < 4; r++)
#pragma unroll
            for (int nd = 0; nd < 4; nd++)
              O[r][m][nd][j] *= a;
        }
    }
    // --- P = exp(S - m), pack bf16, column sum
    float tsum[2] = {0.f, 0.f};
    u32 upk[2][4][2];
#pragma unroll
    for (int nq = 0; nq < 2; nq++)
#pragma unroll
      for (int mk = 0; mk < 4; mk++) {
        float p0 = __expf(sacc[mk][nq][0] - mS[nq]);
        float p1 = __expf(sacc[mk][nq][1] - mS[nq]);
        float p2 = __expf(sacc[mk][nq][2] - mS[nq]);
        float p3 = __expf(sacc[mk][nq][3] - mS[nq]);
        tsum[nq] += (p0 + p1) + (p2 + p3);
        upk[nq][mk][0] = pack2bf(p0, p1);
        upk[nq][mk][1] = pack2bf(p2, p3);
      }
#pragma unroll
    for (int nq = 0; nq < 2; nq++) {
      tsum[nq] += __shfl_xor(tsum[nq], 16);
      tsum[nq] += __shfl_xor(tsum[nq], 32);
      lS[nq] += tsum[nq];
    }
    // --- write P to LDS (row = q_local, keys contiguous), swizzled
#pragma unroll
    for (int nq = 0; nq < 2; nq++)
#pragma unroll
      for (int mk = 0; mk < 4; mk++) {
        int ql  = nq * 16 + l15;
        int sub = mk * 2 + (g >> 1);
        int byteoff = ql * 128 + ((sub ^ (ql & 7)) * 16) + (g & 1) * 8;
        *(uint2*)((char*)Plds + byteoff) = make_uint2(upk[nq][mk][0], upk[nq][mk][1]);
      }
    // --- O[r] += P * V[r], P fragments shared across the 4 heads
#pragma unroll
    for (int kc = 0; kc < 2; kc++) {
      bf16x8 pa[2];
#pragma unroll
      for (int m = 0; m < 2; m++) {
        int ql  = m * 16 + l15;
        int sub = kc * 4 + g;
        pa[m] = *(bf16x8*)((char*)Plds + ql * 128 + ((sub ^ (ql & 7)) * 16));
      }
#pragma unroll
      for (int r = 0; r < 4; r++) {
        bf16x8 vb[4];
#pragma unroll
        for (int nd = 0; nd < 4; nd++) {
          int d = nd * 16 + l15;
          vb[nd] = *(const bf16x8*)(Vb[r] + (size_t)d * S_ + kt * 64 + kc * 32 + g * 8);
        }
#pragma unroll
        for (int m = 0; m < 2; m++)
#pragma unroll
          for (int nd = 0; nd < 4; nd++)
            O[r][m][nd] = __builtin_amdgcn_mfma_f32_16x16x32_bf16(pa[m], vb[nd], O[r][m][nd], 0, 0, 0);
      }
    }
    // --- rotate prefetched K
#pragma unroll
    for (int kc = 0; kc < 2; kc++)
#pragma unroll
      for (int mk = 0; mk < 4; mk++)
        ka[kc][mk] = kan[kc][mk];
  }
  // --- normalize + write fp32 output [b][q][(r*8+hk)*64+d]
  float linv[2];
#pragma unroll
  for (int m = 0; m < 2; m++) linv[m] = 1.0f / lS[m];
#pragma unroll
  for (int m = 0; m < 2; m++)
#pragma unroll
    for (int j = 0; j < 4; j++) {
      float li = __shfl(linv[m], g * 4 + j);
      int q = qb + m * 16 + g * 4 + j;
#pragma unroll
      for (int r = 0; r < 4; r++)
#pragma unroll
        for (int nd = 0; nd < 4; nd++) {
          int d = nd * 16 + l15;
          Out[(size_t)(b * S_ + q) * HID_ + (r * 8 + hk) * 64 + d] = O[r][m][nd][j] * li;
        }
    }
}

// ---------------------------------------------------------------- launch
extern "C" void kernel_launch(void* const* d_in, const int* in_sizes, int n_in,
                              void* d_out, int out_size, void* d_ws, size_t ws_size,
                              hipStream_t stream) {
  const float* hs  = (const float*)d_in[0];
  const int*   pos = (const int*)d_in[1];
  const float* Wq  = (const float*)d_in[2];
  const float* Wk  = (const float*)d_in[3];
  const float* Wv  = (const float*)d_in[4];
  float* out = (float*)d_out;
  char* ws = (char*)d_ws;
  u16* Abf = (u16*)(ws + 0);          // 16,777,216
  u16* Wt  = (u16*)(ws + 16777216);   // 12,582,912
  u16* QKV = (u16*)(ws + 29360128);   // 25,165,824
  u16* Qr  = (u16*)(ws + 54525952);   // 4,194,304
  u16* Kr  = (u16*)(ws + 58720256);   // 4,194,304
  u16* Vt  = (u16*)(ws + 62914560);   // 16,777,216

  cvtA_kernel<<<dim3(2048), dim3(256), 0, stream>>>(hs, Abf);
  cvtW_kernel<<<dim3(96, 64), dim3(32, 8), 0, stream>>>(Wq, Wk, Wv, Wt);
  gemm_kernel<<<dim3(24, 32), dim3(256), 0, stream>>>(Abf, Wt, QKV);
  rope_kernel<<<dim3(4096), dim3(128), 0, stream>>>(QKV, pos, Qr, Kr);
  transV_kernel<<<dim3(32, 32, 2), dim3(256), 0, stream>>>(QKV, Vt);
  attn_kernel<<<dim3(64, 8, 2), dim3(64), 0, stream>>>(Qr, Kr, Vt, out);
}